// Round 15
// baseline (838.638 us; speedup 1.0000x reference)
//
#include <hip/hip_runtime.h>
#include <math.h>

#define B_ 4
#define C_ 64
#define C2_ 128
#define C6_ 384
#define H_ 256
#define Wd_ 256
#define HW_ 65536
#define MIP_ 8
#define BNINV 0.9999950000374994f

typedef short bf16x8 __attribute__((ext_vector_type(8)));
typedef float f32x4 __attribute__((ext_vector_type(4)));
typedef unsigned short u16x8 __attribute__((ext_vector_type(8)));
typedef unsigned short u16x4 __attribute__((ext_vector_type(4)));
typedef unsigned int   u32x4 __attribute__((ext_vector_type(4)));

__device__ __forceinline__ float sigm(float x){ return 1.f/(1.f+expf(-x)); }
__device__ __forceinline__ float gelu_f(float x){ return 0.5f*x*(1.f+erff(x*0.7071067811865476f)); }
__device__ __forceinline__ unsigned short bfrnd(float f){
  unsigned u = __float_as_uint(f);
  unsigned r = u + 0x7FFFu + ((u>>16)&1u);
  return (unsigned short)(r>>16);
}
__device__ __forceinline__ float bf2f(unsigned short s){
  return __uint_as_float(((unsigned)s)<<16);
}

// ---------------- CA branch ----------------
__global__ void __launch_bounds__(256) k_xstat(const float* __restrict__ x,
                                               float* __restrict__ xh, float* __restrict__ xw){
  int plane = blockIdx.x;
  int tid = threadIdx.x;
  const float* p = x + (size_t)plane*HW_;
  float cs = 0.f;
  for(int h=0;h<256;h++) cs += p[h*256+tid];
  xw[plane*256+tid] = cs*(1.f/256.f);
  float rs = 0.f;
  const f32x4* pr4 = (const f32x4*)(p + (size_t)tid*256);
  #pragma unroll 8
  for(int w=0;w<64;w++){ f32x4 v = pr4[w]; rs += v[0]+v[1]+v[2]+v[3]; }
  xh[plane*256+tid] = rs*(1.f/256.f);
}

__global__ void k_ca_t(const float* __restrict__ xh, const float* __restrict__ xw,
                       const float* __restrict__ w1, const float* __restrict__ b1,
                       const float* __restrict__ bng, const float* __restrict__ bnb,
                       float* __restrict__ t){
  int idx = blockIdx.x*256 + threadIdx.x;
  int p = idx & 511; int m = (idx>>9)&7; int b = idx>>12;
  float acc = b1[m];
  #pragma unroll 8
  for(int c=0;c<C_;c++){
    float yv = (p<256) ? xh[(b*C_+c)*256 + p] : xw[(b*C_+c)*256 + (p-256)];
    acc += w1[m*C_+c]*yv;
  }
  float v = acc*BNINV*bng[m] + bnb[m];
  t[idx] = v * fminf(fmaxf(v+3.f,0.f),6.f)*(1.f/6.f);
}

__global__ void k_ca_a(const float* __restrict__ t,
                       const float* __restrict__ wh, const float* __restrict__ bh,
                       const float* __restrict__ ww, const float* __restrict__ bw,
                       float* __restrict__ ah, float* __restrict__ aw){
  int idx = blockIdx.x*256 + threadIdx.x;
  int p = idx & 511; int co = (idx>>9)&63; int b = idx>>15;
  bool isH = (p<256);
  const float* wm = isH ? wh : ww;
  float acc = isH ? bh[co] : bw[co];
  #pragma unroll
  for(int m=0;m<MIP_;m++) acc += wm[co*MIP_+m]*t[(b*MIP_+m)*512+p];
  float s = sigm(acc);
  if(isH) ah[(b*C_+co)*256+p] = s; else aw[(b*C_+co)*256+(p-256)] = s;
}

// ---------------- weight / input prep (once) ----------------
__global__ void __launch_bounds__(256) k_xprep(const float* __restrict__ x, unsigned short* __restrict__ xb){
  __shared__ float sm[64][65];
  int tid = threadIdx.x;
  int img = blockIdx.x >> 10;
  int p0 = (blockIdx.x & 1023)*64;
  int lane = tid & 63, wq = tid >> 6;
  #pragma unroll
  for(int cc=0; cc<16; ++cc){
    int c = cc*4 + wq;
    sm[c][lane] = x[(size_t)(img*C_+c)*HW_ + p0 + lane];
  }
  __syncthreads();
  int pl = tid >> 2;
  int c0 = (tid & 3) * 16;
  u16x8 lo, hi;
  #pragma unroll
  for(int i=0;i<8;i++)  lo[i] = bfrnd(sm[c0+i][pl]);
  #pragma unroll
  for(int i=0;i<8;i++)  hi[i] = bfrnd(sm[c0+8+i][pl]);
  unsigned short* dst = xb + ((size_t)img*HW_ + p0 + pl)*64 + c0;
  *(u16x8*)(dst)     = lo;
  *(u16x8*)(dst + 8) = hi;
}

__global__ void k_wprep(const float* __restrict__ w, unsigned short* __restrict__ wbt){
  int t = blockIdx.x*256 + threadIdx.x;   // 16384
  const float* src = w + (size_t)t*9;
  int oc = t >> 7, ic = t & 127;
  #pragma unroll
  for(int tap=0; tap<9; ++tap)
    wbt[(size_t)(tap*128+oc)*128 + ic] = bfrnd(src[tap]);
}

__global__ void k_wprep2(const float* __restrict__ pw, const float* __restrict__ w2,
                         const float* __restrict__ hw, unsigned short* __restrict__ pwb,
                         unsigned short* __restrict__ w2b, unsigned short* __restrict__ wb1){
  int t = blockIdx.x*256 + threadIdx.x;   // 24576
  if(t < 8192){ pwb[t] = bfrnd(pw[t]); w2b[t] = bfrnd(w2[t]); }
  wb1[t] = bfrnd(hw[t]);
}

// ---------------- FSAS chain (bf16, pixel-major) ----------------
// FUSED hid0 (1x1 conv 64->384 via MFMA, into LDS with 3x3 halo) + depthwise 3x3.
// block: 64-px run x 128 oc (grid y = 3 covers 384). LDS [3][66][136] bf16.
__global__ void __launch_bounds__(256) k_hiddw(const unsigned short* __restrict__ xb,
                                               const unsigned short* __restrict__ wb1,
                                               const float* __restrict__ wd,
                                               unsigned short* __restrict__ hidb){
  __shared__ __align__(16) unsigned short sH[3][66][136];
  int tid = threadIdx.x;
  int lane = tid & 63, wid = tid >> 6;
  int l15 = lane & 15, lk = lane >> 4;
  int p0 = blockIdx.x*64;
  int h  = p0 >> 8;
  int w0 = p0 & 255;
  int ocb = blockIdx.y*128;

  // phase A: hid0 for rows h-1..h+1, cols w0-1..w0+64, oc [ocb, ocb+128)
  const unsigned short* wA0 = wb1 + (size_t)(ocb + (wid*2+0)*16 + l15)*64 + lk*8;
  const unsigned short* wA1 = wb1 + (size_t)(ocb + (wid*2+1)*16 + l15)*64 + lk*8;
  #pragma unroll
  for(int pos=0; pos<15; ++pos){
    int row = pos/5, nt = pos - (pos/5)*5;
    int rg = h + row - 1;
    int px_local = nt*16 + l15;
    int colg = w0 - 1 + px_local;
    bool ok = ((unsigned)rg < 256u) && ((unsigned)colg < 256u);
    f32x4 a0 = (f32x4)0.f, a1 = (f32x4)0.f;
    #pragma unroll
    for(int kk=0; kk<2; ++kk){
      bf16x8 bfr = {0,0,0,0,0,0,0,0};
      if(ok) bfr = *(const bf16x8*)(xb + (size_t)(rg*256 + colg)*64 + kk*32 + lk*8);
      bf16x8 af0 = *(const bf16x8*)(wA0 + kk*32);
      bf16x8 af1 = *(const bf16x8*)(wA1 + kk*32);
      a0 = __builtin_amdgcn_mfma_f32_16x16x32_bf16(af0, bfr, a0, 0,0,0);
      a1 = __builtin_amdgcn_mfma_f32_16x16x32_bf16(af1, bfr, a1, 0,0,0);
    }
    if(px_local < 66){
      u16x4 v0, v1;
      #pragma unroll
      for(int r=0;r<4;r++){ v0[r]=bfrnd(a0[r]); v1[r]=bfrnd(a1[r]); }
      *(u16x4*)&sH[row][px_local][(wid*2+0)*16 + lk*4] = v0;
      *(u16x4*)&sH[row][px_local][(wid*2+1)*16 + lk*4] = v1;
    }
  }
  __syncthreads();

  // phase B: depthwise 3x3 from LDS. thread: 8 ch x 4 px.
  int cg = tid & 15;
  int tg = tid >> 4;
  int chb = ocb + cg*8;
  float wreg[72];
  {
    const f32x4* wsrc = (const f32x4*)(wd + (size_t)chb*9);
    #pragma unroll
    for(int i=0;i<18;i++){
      f32x4 v = wsrc[i];
      wreg[4*i+0]=v[0]; wreg[4*i+1]=v[1]; wreg[4*i+2]=v[2]; wreg[4*i+3]=v[3];
    }
  }
  float acc[4][8];
  #pragma unroll
  for(int px=0;px<4;px++)
    #pragma unroll
    for(int e=0;e<8;e++) acc[px][e] = 0.f;

  #pragma unroll
  for(int ky=0; ky<3; ++ky){
    float row6[6][8];
    #pragma unroll
    for(int c6=0; c6<6; ++c6){
      u16x8 v8 = *(const u16x8*)&sH[ky][tg*4 + c6][cg*8];
      #pragma unroll
      for(int e=0;e<8;e++) row6[c6][e] = bf2f(v8[e]);
    }
    #pragma unroll
    for(int kx=0; kx<3; ++kx){
      #pragma unroll
      for(int px=0; px<4; ++px){
        #pragma unroll
        for(int e=0;e<8;e++)
          acc[px][e] += row6[px+kx][e] * wreg[e*9 + ky*3 + kx];
      }
    }
  }
  #pragma unroll
  for(int px=0; px<4; ++px){
    u16x8 o8;
    #pragma unroll
    for(int e=0;e<8;e++) o8[e] = bfrnd(acc[px][e]);
    *(u16x8*)(hidb + (size_t)(p0 + tg*4 + px)*384 + chb) = o8;
  }
}

// circular 8x8 conv per patch
__global__ void __launch_bounds__(256) k_circ_bf(const unsigned short* __restrict__ hidb,
                                                 unsigned short* __restrict__ ob){
  __shared__ __align__(16) unsigned short lq[2][64][128];
  __shared__ __align__(16) unsigned short lkk[2][64][128];
  int tid = threadIdx.x;
  #pragma unroll
  for(int it=0; it<8; ++it){
    int s = it*256 + tid;
    int which = s >> 10, rem = s & 1023;
    int pix = rem >> 4, cg = rem & 15;
    int gp = blockIdx.x*2 + which;
    int ph = gp >> 5, pw = gp & 31;
    size_t pg = (size_t)((ph*8 + (pix>>3))*256 + pw*8 + (pix&7));
    *(u16x8*)&lq[which][pix][cg*8]  = *(const u16x8*)(hidb + pg*384 + cg*8);
    *(u16x8*)&lkk[which][pix][cg*8] = *(const u16x8*)(hidb + pg*384 + 128 + cg*8);
  }
  __syncthreads();
  int which = tid >> 7, c = tid & 127;
  float kr[64];
  #pragma unroll
  for(int pix=0;pix<64;pix++) kr[pix] = bf2f(lkk[which][pix][c]);
  float outv[64];
  #pragma unroll
  for(int t2=0;t2<64;t2++) outv[t2] = 0.f;
  #pragma unroll
  for(int u=0;u<8;u++){
    #pragma unroll
    for(int v=0;v<8;v++){
      float qv = bf2f(lq[which][u*8+v][c]);
      #pragma unroll
      for(int i=0;i<8;i++){
        #pragma unroll
        for(int j=0;j<8;j++)
          outv[i*8+j] += qv * kr[((i-u)&7)*8 + ((j-v)&7)];
      }
    }
  }
  __syncthreads();
  #pragma unroll
  for(int t2=0;t2<64;t2++) lq[which][t2][c] = bfrnd(outv[t2]);
  __syncthreads();
  #pragma unroll
  for(int it=0; it<8; ++it){
    int s = it*256 + tid;
    int which2 = s >> 10, rem = s & 1023;
    int pix = rem >> 4, cg = rem & 15;
    int gp = blockIdx.x*2 + which2;
    int ph = gp >> 5, pw = gp & 31;
    size_t pg = (size_t)((ph*8 + (pix>>3))*256 + pw*8 + (pix&7));
    *(u16x8*)(ob + pg*128 + cg*8) = *(u16x8*)&lq[which2][pix][cg*8];
  }
}

// fused LN + (v*on) + proj via MFMA
__global__ void __launch_bounds__(256) k_proj_mfma(const unsigned short* __restrict__ ob,
                      const unsigned short* __restrict__ hidb,
                      const float* __restrict__ lnw, const float* __restrict__ lnb,
                      const unsigned short* __restrict__ pwb, unsigned short* __restrict__ catb){
  __shared__ unsigned int lds32[256*64];
  int tid = threadIdx.x;
  int lane = tid & 63, wid = tid >> 6;
  int p0 = blockIdx.x*256;
  {
    int p = p0 + tid;
    u16x8 o8[16];
    #pragma unroll
    for(int g=0; g<16; ++g) o8[g] = *(const u16x8*)(ob + (size_t)p*128 + g*8);
    float s=0.f, s2=0.f;
    #pragma unroll
    for(int g=0; g<16; ++g)
      #pragma unroll
      for(int e=0; e<8; ++e){ float v = bf2f(o8[g][e]); s += v; s2 += v*v; }
    float m = s*(1.f/C2_);
    float var = s2*(1.f/C2_) - m*m;
    float rs = rsqrtf(var + 1e-5f);
    #pragma unroll
    for(int cg=0; cg<16; ++cg){
      u16x8 v8 = *(const u16x8*)(hidb + (size_t)p*384 + 256 + cg*8);
      unsigned uu[4];
      #pragma unroll
      for(int ee=0; ee<4; ++ee){
        int c = cg*8 + ee*2;
        float on0 = (bf2f(o8[cg][2*ee])   - m)*rs*lnw[c]   + lnb[c];
        float on1 = (bf2f(o8[cg][2*ee+1]) - m)*rs*lnw[c+1] + lnb[c+1];
        float vn0 = bf2f(v8[2*ee])*on0;
        float vn1 = bf2f(v8[2*ee+1])*on1;
        uu[ee] = (unsigned)bfrnd(vn0) | ((unsigned)bfrnd(vn1)<<16);
      }
      int blk = cg ^ (tid & 15);
      u32x4 w4 = {uu[0],uu[1],uu[2],uu[3]};
      *(u32x4*)&lds32[tid*64 + blk*4] = w4;
    }
  }
  __syncthreads();
  int l15 = lane & 15, lk = lane >> 4;
  f32x4 acc[4][4];
  #pragma unroll
  for(int m=0;m<4;m++)
    #pragma unroll
    for(int n=0;n<4;n++) acc[m][n] = (f32x4)0.f;
  int plb = wid*64;
  #pragma unroll
  for(int kk=0; kk<4; ++kk){
    bf16x8 bfr[4];
    #pragma unroll
    for(int n=0;n<4;n++){
      int pl = plb + n*16 + l15;
      int blk = (kk*4 + lk) ^ l15;
      bfr[n] = *(bf16x8*)&lds32[pl*64 + blk*4];
    }
    #pragma unroll
    for(int m=0;m<4;m++){
      bf16x8 af = *(const bf16x8*)(pwb + (size_t)(m*16+l15)*128 + kk*32 + lk*8);
      #pragma unroll
      for(int n=0;n<4;n++)
        acc[m][n] = __builtin_amdgcn_mfma_f32_16x16x32_bf16(af, bfr[n], acc[m][n], 0,0,0);
    }
  }
  #pragma unroll
  for(int n=0;n<4;n++){
    int p = p0 + plb + n*16 + l15;
    #pragma unroll
    for(int m=0;m<4;m++){
      u16x4 v;
      #pragma unroll
      for(int r=0;r<4;r++) v[r] = bfrnd(acc[m][n][r]);
      *(u16x4*)(catb + (size_t)p*128 + 64 + m*16 + lk*4) = v;
    }
  }
}

__global__ void __launch_bounds__(256) k_caout_bf(const float* __restrict__ x, const float* __restrict__ ah,
                        const float* __restrict__ aw, unsigned short* __restrict__ catb, int b){
  __shared__ float sm[64][65];
  int tid = threadIdx.x;
  int p0 = blockIdx.x*64;
  int h = p0 >> 8;
  int wbase = p0 & 255;
  int lane = tid & 63, wq = tid >> 6;
  #pragma unroll
  for(int cc=0; cc<16; ++cc){
    int c = cc*4 + wq;
    float v = x[(size_t)(b*C_+c)*HW_ + p0 + lane];
    v *= ah[(b*C_+c)*256 + h] * aw[(b*C_+c)*256 + wbase + lane];
    sm[c][lane] = v;
  }
  __syncthreads();
  int pl = tid >> 2;
  int c0 = (tid & 3) * 16;
  u16x8 lo, hi;
  #pragma unroll
  for(int i=0;i<8;i++)  lo[i] = bfrnd(sm[c0+i][pl]);
  #pragma unroll
  for(int i=0;i<8;i++)  hi[i] = bfrnd(sm[c0+8+i][pl]);
  unsigned short* dst = catb + (size_t)(p0+pl)*128 + c0;
  *(u16x8*)(dst)     = lo;
  *(u16x8*)(dst + 8) = hi;
}

// 3x3 conv 128->128 pad1 via MFMA, conflict-free LDS layout + T14 stage-ahead.
__global__ void __launch_bounds__(256,3) k_fus1_mfma(const unsigned short* __restrict__ catb,
                                                     const unsigned short* __restrict__ wbt,
                                                     unsigned short* __restrict__ f1b){
  __shared__ __align__(16) unsigned short sA[3][130][32];
  int tid = threadIdx.x;
  int lane = tid & 63, wid = tid >> 6;
  int wm = wid & 1, wn = wid >> 1;
  int bid = blockIdx.x;
  int xcd = bid & 7, idx = bid >> 3;    // 0..127
  int h   = xcd*32 + (idx >> 2);
  int w0  = ((idx >> 1) & 1) * 128;
  int ocb = (idx & 1) * 64 + wn*32;
  int l15 = lane & 15, lk = lane >> 4;

  int srow[7], spxl[7], sicq[7];
  bool sok[7], sld[7];
  #pragma unroll
  for(int it=0; it<7; ++it){
    int s = it*256 + tid;
    sok[it] = (s < 1560);
    int row = s/520;
    int rem = s - row*520;
    int pxl = rem >> 2;
    int icq = rem & 3;
    srow[it]=row; spxl[it]=pxl; sicq[it]=icq;
    int r = h + row - 1;
    int c = w0 + pxl - 1;
    sld[it] = sok[it] && (unsigned)r < 256u && (unsigned)c < 256u;
  }

  u16x8 st[7];
  #pragma unroll
  for(int it=0; it<7; ++it){
    u16x8 v = {0,0,0,0,0,0,0,0};
    if(sld[it]){
      int r = h + srow[it] - 1, c = w0 + spxl[it] - 1;
      v = *(const u16x8*)(catb + (size_t)(r*256 + c)*128 + sicq[it]*8);
    }
    st[it] = v;
  }

  f32x4 acc[4][2];
  #pragma unroll
  for(int i=0;i<4;i++)
    #pragma unroll
    for(int j=0;j<2;j++) acc[i][j] = (f32x4)0.f;

  const unsigned short* wbase = wbt + (size_t)(ocb + l15)*128 + lk*8;

  for(int icc=0; icc<4; ++icc){
    int ic0 = icc*32;
    __syncthreads();
    #pragma unroll
    for(int it=0; it<7; ++it){
      if(sok[it]){
        int blk = sicq[it] ^ ((spxl[it]>>1)&3);
        *(u16x8*)&sA[srow[it]][spxl[it]][blk*8] = st[it];
      }
    }
    __syncthreads();
    if(icc < 3){
      int ic0n = (icc+1)*32;
      #pragma unroll
      for(int it=0; it<7; ++it){
        u16x8 v = {0,0,0,0,0,0,0,0};
        if(sld[it]){
          int r = h + srow[it] - 1, c = w0 + spxl[it] - 1;
          v = *(const u16x8*)(catb + (size_t)(r*256 + c)*128 + ic0n + sicq[it]*8);
        }
        st[it] = v;
      }
    }
    #pragma unroll
    for(int ky=0; ky<3; ++ky){
      bf16x8 wf[3][2];
      #pragma unroll
      for(int kx=0; kx<3; ++kx){
        const unsigned short* wt = wbase + (size_t)(ky*3+kx)*16384 + ic0;
        wf[kx][0] = *(const bf16x8*)(wt);
        wf[kx][1] = *(const bf16x8*)(wt + 2048);
      }
      #pragma unroll
      for(int kx=0; kx<3; ++kx){
        #pragma unroll
        for(int i=0;i<4;++i){
          int rr = wm*64 + i*16 + l15 + kx;
          int blk = lk ^ ((rr>>1)&3);
          bf16x8 a = *(const bf16x8*)&sA[ky][rr][blk*8];
          acc[i][0] = __builtin_amdgcn_mfma_f32_16x16x32_bf16(wf[kx][0], a, acc[i][0], 0,0,0);
          acc[i][1] = __builtin_amdgcn_mfma_f32_16x16x32_bf16(wf[kx][1], a, acc[i][1], 0,0,0);
        }
      }
    }
  }
  #pragma unroll
  for(int i=0;i<4;i++){
    int sp = h*256 + w0 + wm*64 + i*16 + l15;
    #pragma unroll
    for(int j=0;j<2;j++){
      u16x4 v;
      #pragma unroll
      for(int r2=0;r2<4;r2++) v[r2] = bfrnd(acc[i][j][r2]);
      *(u16x4*)(f1b + (size_t)sp*128 + ocb + j*16 + lk*4) = v;
    }
  }
}

// fus2: g = gelu(bn1(f1)); z = x + rs*bn2(conv1x1(g)) -> bf16 z, fused CBAM partials
__global__ void __launch_bounds__(256) k_fus2_mfma(const unsigned short* __restrict__ f1b,
                      const float* __restrict__ x, const unsigned short* __restrict__ w2b,
                      const float* __restrict__ bn1g, const float* __restrict__ bn1b,
                      const float* __restrict__ bn2g, const float* __restrict__ bn2b,
                      const float* __restrict__ rscale, unsigned short* __restrict__ zb,
                      float* __restrict__ psum2, float* __restrict__ pmax2, int b){
  __shared__ unsigned int lds32[128*64];
  __shared__ float smp[4][4][16], smm[4][4][16];
  int tid = threadIdx.x;
  int lane = tid & 63, wid = tid >> 6;
  int p0 = blockIdx.x*128;
  int ic0 = (tid & 15) * 8;
  #pragma unroll
  for(int pass=0; pass<8; ++pass){
    int pl = pass*16 + (tid>>4);
    bf16x8 vv = *(const bf16x8*)(f1b + (size_t)(p0+pl)*128 + ic0);
    unsigned uu[4];
    #pragma unroll
    for(int ee=0; ee<4; ++ee){
      float f0 = bf2f((unsigned short)vv[2*ee])  *BNINV*bn1g[ic0+2*ee]   + bn1b[ic0+2*ee];
      float f1 = bf2f((unsigned short)vv[2*ee+1])*BNINV*bn1g[ic0+2*ee+1] + bn1b[ic0+2*ee+1];
      uu[ee] = (unsigned)bfrnd(gelu_f(f0)) | ((unsigned)bfrnd(gelu_f(f1))<<16);
    }
    int blk = (ic0>>3) ^ (pl&15);
    u32x4 w4 = {uu[0],uu[1],uu[2],uu[3]};
    *(u32x4*)&lds32[pl*64 + blk*4] = w4;
  }
  __syncthreads();
  int l15 = lane & 15, lk = lane >> 4;
  f32x4 acc[4][2];
  #pragma unroll
  for(int m=0;m<4;m++)
    #pragma unroll
    for(int n=0;n<2;n++) acc[m][n] = (f32x4)0.f;
  int pl0 = wid*32 + l15;
  #pragma unroll
  for(int kk=0; kk<4; ++kk){
    bf16x8 bfr[2];
    #pragma unroll
    for(int n=0;n<2;n++){
      int pl = pl0 + n*16;
      int blk = (kk*4 + lk) ^ l15;
      bfr[n] = *(bf16x8*)&lds32[pl*64 + blk*4];
    }
    #pragma unroll
    for(int m=0;m<4;m++){
      bf16x8 af = *(const bf16x8*)(w2b + (size_t)(m*16+l15)*128 + kk*32 + lk*8);
      #pragma unroll
      for(int n=0;n<2;n++)
        acc[m][n] = __builtin_amdgcn_mfma_f32_16x16x32_bf16(af, bfr[n], acc[m][n], 0,0,0);
    }
  }
  float rs = rscale[0];
  float ps[4][4], pm[4][4];
  #pragma unroll
  for(int m=0;m<4;m++)
    #pragma unroll
    for(int r=0;r<4;r++){ ps[m][r]=0.f; pm[m][r]=-INFINITY; }
  #pragma unroll
  for(int n=0;n<2;n++){
    int p = p0 + pl0 + n*16;
    #pragma unroll
    for(int m=0;m<4;m++){
      #pragma unroll
      for(int r=0;r<4;r++){
        int oc = m*16 + lk*4 + r;
        float f = acc[m][n][r]*BNINV*bn2g[oc] + bn2b[oc];
        float zv = x[(size_t)(b*C_+oc)*HW_ + p] + rs*f;
        zb[(size_t)oc*HW_ + p] = bfrnd(zv);
        ps[m][r] += zv; pm[m][r] = fmaxf(pm[m][r], zv);
      }
    }
  }
  #pragma unroll
  for(int off=1; off<16; off<<=1){
    #pragma unroll
    for(int m=0;m<4;m++)
      #pragma unroll
      for(int r=0;r<4;r++){
        ps[m][r] += __shfl_xor(ps[m][r], off, 64);
        pm[m][r] = fmaxf(pm[m][r], __shfl_xor(pm[m][r], off, 64));
      }
  }
  if(l15 == 0){
    #pragma unroll
    for(int m=0;m<4;m++)
      #pragma unroll
      for(int r=0;r<4;r++){
        smp[wid][lk][m*4+r] = ps[m][r];
        smm[wid][lk][m*4+r] = pm[m][r];
      }
  }
  __syncthreads();
  if(tid < 64){
    int m = tid>>4, lkg = (tid>>2)&3, r = tid&3;
    float s = 0.f, mx = -INFINITY;
    #pragma unroll
    for(int w=0;w<4;w++){
      s += smp[w][lkg][m*4+r];
      mx = fmaxf(mx, smm[w][lkg][m*4+r]);
    }
    psum2[blockIdx.x*64 + tid] = s;
    pmax2[blockIdx.x*64 + tid] = mx;
  }
}

// ---------------- CBAM + epilogue (batched over 4 images) ----------------
__global__ void k_cbamred2(const float* __restrict__ psum2, const float* __restrict__ pmax2,
                           float* __restrict__ avgb4, float* __restrict__ maxb4){
  int c = blockIdx.x & 63; int b = blockIdx.x >> 6;
  const float* ps = psum2 + (size_t)b*32768;
  const float* pmx = pmax2 + (size_t)b*32768;
  int tid = threadIdx.x;  // 256
  float s = ps[(size_t)tid*64 + c] + ps[(size_t)(tid+256)*64 + c];
  float m = fmaxf(pmx[(size_t)tid*64 + c], pmx[(size_t)(tid+256)*64 + c]);
  __shared__ float ss[256], sm[256];
  ss[tid]=s; sm[tid]=m; __syncthreads();
  for(int off=128; off>0; off>>=1){
    if(tid<off){ ss[tid]+=ss[tid+off]; sm[tid]=fmaxf(sm[tid],sm[tid+off]); }
    __syncthreads();
  }
  if(tid==0){ avgb4[b*64+c]=ss[0]*(1.f/HW_); maxb4[b*64+c]=sm[0]; }
}

__global__ void k_cbammlp(const float* __restrict__ avgb4, const float* __restrict__ maxb4,
                          const float* __restrict__ w1, const float* __restrict__ w2,
                          float* __restrict__ catt4){
  __shared__ float h1s[4][8];
  int tid = threadIdx.x;   // 256 = 4 batches x 64 ch
  int b = tid >> 6, cl = tid & 63;
  if(cl < 8){
    const float* src = (cl<4)? avgb4 + b*64 : maxb4 + b*64;
    int r = cl & 3;
    float s = 0.f;
    for(int c=0;c<C_;c++) s += w1[r*C_+c]*src[c];
    h1s[b][cl] = fmaxf(s,0.f);
  }
  __syncthreads();
  float a = 0.f;
  #pragma unroll
  for(int r=0;r<4;r++) a += w2[cl*4+r]*(h1s[b][r]+h1s[b][r+4]);
  catt4[b*64+cl] = sigm(a);
}

__global__ void k_chatt(const unsigned short* __restrict__ z4, const float* __restrict__ catt4,
                        float* __restrict__ samean4, float* __restrict__ samax4){
  int gp = blockIdx.x*256 + threadIdx.x;   // 0..262143
  int b = gp >> 16; int p = gp & 65535;
  const unsigned short* zb = z4 + (size_t)b*C_*HW_;
  const float* ct = catt4 + b*64;
  float s = 0.f, m = -INFINITY;
  #pragma unroll 8
  for(int c=0;c<C_;c++){
    float v = bf2f(zb[(size_t)c*HW_+p])*ct[c];
    s += v; m = fmaxf(m,v);
  }
  samean4[gp] = s*(1.f/C_);
  samax4[gp] = m;
}

__global__ void k_saconv(const float* __restrict__ samean4, const float* __restrict__ samax4,
                         const float* __restrict__ saw, float* __restrict__ att4){
  int gp = blockIdx.x*256 + threadIdx.x;
  int b = gp >> 16; int p = gp & 65535;
  int base = b << 16;
  int h = p>>8, w = p&255;
  float acc = 0.f;
  #pragma unroll
  for(int ky=0;ky<7;ky++){
    int hh = h+ky-3; if((unsigned)hh>=256u) continue;
    #pragma unroll
    for(int kx=0;kx<7;kx++){
      int ww2 = w+kx-3; if((unsigned)ww2>=256u) continue;
      int q = base + hh*256+ww2;
      acc += samean4[q]*saw[ky*7+kx] + samax4[q]*saw[49+ky*7+kx];
    }
  }
  att4[gp] = sigm(acc);
}

__global__ void k_final(const unsigned short* __restrict__ z4, const float* __restrict__ catt4,
                        const float* __restrict__ att4, float* __restrict__ out){
  int gp = blockIdx.x*256 + threadIdx.x;   // (b,p)
  int b = gp >> 16; int p = gp & 65535;
  int c = blockIdx.y;
  float v = bf2f(z4[((size_t)(b*C_+c))*HW_ + p]) * catt4[b*64+c] * att4[gp];
  out[((size_t)(b*C_+c))*HW_ + p] = gelu_f(v);
}

extern "C" void kernel_launch(void* const* d_in, const int* in_sizes, int n_in,
                              void* d_out, int out_size, void* d_ws, size_t ws_size,
                              hipStream_t stream){
  const float* x            = (const float*)d_in[0];
  const float* ca_conv1_w   = (const float*)d_in[1];
  const float* ca_conv1_b   = (const float*)d_in[2];
  const float* ca_bn_g      = (const float*)d_in[3];
  const float* ca_bn_b      = (const float*)d_in[4];
  const float* ca_convh_w   = (const float*)d_in[5];
  const float* ca_convh_b   = (const float*)d_in[6];
  const float* ca_convw_w   = (const float*)d_in[7];
  const float* ca_convw_b   = (const float*)d_in[8];
  const float* fsas_hidden_w= (const float*)d_in[9];
  const float* fsas_dw_w    = (const float*)d_in[10];
  const float* fsas_proj_w  = (const float*)d_in[11];
  const float* ln_w         = (const float*)d_in[12];
  const float* ln_b         = (const float*)d_in[13];
  const float* fus_conv1_w  = (const float*)d_in[14];
  const float* fus_bn1_g    = (const float*)d_in[15];
  const float* fus_bn1_b    = (const float*)d_in[16];
  const float* fus_conv2_w  = (const float*)d_in[17];
  const float* fus_bn2_g    = (const float*)d_in[18];
  const float* fus_bn2_b    = (const float*)d_in[19];
  const float* cbam_mlp1_w  = (const float*)d_in[20];
  const float* cbam_mlp2_w  = (const float*)d_in[21];
  const float* cbam_sa_w    = (const float*)d_in[22];
  const float* rscale       = (const float*)d_in[23];
  float* out = (float*)d_out;
  float* ws  = (float*)d_ws;

  float* xh      = ws + 0;        // 65536
  float* xw      = ws + 65536;    // 65536
  float* t       = ws + 131072;   // 16384
  float* ah      = ws + 147456;   // 65536
  float* aw      = ws + 212992;   // 65536
  float* catt4   = ws + 278528;   // 256
  float* avgb4   = ws + 278784;   // 256
  float* maxb4   = ws + 279040;   // 256
  float* psum2   = ws + 279296;   // 4*32768
  float* pmax2   = ws + 410368;   // 4*32768
  float* samean4 = ws + 541440;   // 262144
  float* samax4  = ws + 803584;   // 262144
  float* att4    = ws + 1065728;  // 262144
  float* big     = ws + 1327872;
  unsigned short* catb  = (unsigned short*)(big);             // [HW][128] u16
  unsigned short* f1b   = (unsigned short*)(big + 4194304);   // [HW][128] u16
  unsigned short* z4    = (unsigned short*)(big + 8388608);   // [4][64][HW] u16
  unsigned short* xb    = (unsigned short*)(big + 16777216);  // [4*HW][64] u16
  unsigned short* hidb  = (unsigned short*)(big + 25165824);  // [HW][384] u16
  unsigned short* obuf  = (unsigned short*)(big + 37748736);  // [HW][128] u16
  unsigned short* wbt   = (unsigned short*)(big + 41943040);  // 147456 u16
  unsigned short* wb1   = (unsigned short*)(big + 42016768);  // 24576 u16
  unsigned short* pwb   = (unsigned short*)(big + 42029056);  // 8192 u16
  unsigned short* w2b   = (unsigned short*)(big + 42033152);  // 8192 u16

  k_xstat<<<256,256,0,stream>>>(x, xh, xw);
  k_ca_t<<<64,256,0,stream>>>(xh, xw, ca_conv1_w, ca_conv1_b, ca_bn_g, ca_bn_b, t);
  k_ca_a<<<512,256,0,stream>>>(t, ca_convh_w, ca_convh_b, ca_convw_w, ca_convw_b, ah, aw);
  k_xprep<<<4096,256,0,stream>>>(x, xb);
  k_wprep<<<64,256,0,stream>>>(fus_conv1_w, wbt);
  k_wprep2<<<96,256,0,stream>>>(fsas_proj_w, fus_conv2_w, fsas_hidden_w, pwb, w2b, wb1);

  for(int b=0;b<4;b++){
    k_hiddw<<<dim3(1024,3),256,0,stream>>>(xb + (size_t)b*HW_*64, wb1, fsas_dw_w, hidb);
    k_circ_bf<<<512,256,0,stream>>>(hidb, obuf);
    k_proj_mfma<<<256,256,0,stream>>>(obuf, hidb, ln_w, ln_b, pwb, catb);
    k_caout_bf<<<1024,256,0,stream>>>(x, ah, aw, catb, b);
    k_fus1_mfma<<<1024,256,0,stream>>>(catb, wbt, f1b);
    k_fus2_mfma<<<512,256,0,stream>>>(f1b, x, w2b, fus_bn1_g, fus_bn1_b, fus_bn2_g, fus_bn2_b,
                                      rscale, z4 + (size_t)b*C_*HW_,
                                      psum2 + (size_t)b*32768, pmax2 + (size_t)b*32768, b);
  }

  k_cbamred2<<<256,256,0,stream>>>(psum2, pmax2, avgb4, maxb4);
  k_cbammlp<<<1,256,0,stream>>>(avgb4, maxb4, cbam_mlp1_w, cbam_mlp2_w, catt4);
  k_chatt<<<1024,256,0,stream>>>(z4, catt4, samean4, samax4);
  k_saconv<<<1024,256,0,stream>>>(samean4, samax4, cbam_sa_w, att4);
  k_final<<<dim3(1024,64),256,0,stream>>>(z4, catt4, att4, out);
}

// Round 16
// 765.119 us; speedup vs baseline: 1.0961x; 1.0961x over previous
//
#include <hip/hip_runtime.h>
#include <math.h>

#define B_ 4
#define C_ 64
#define C2_ 128
#define C6_ 384
#define H_ 256
#define Wd_ 256
#define HW_ 65536
#define MIP_ 8
#define BNINV 0.9999950000374994f

typedef short bf16x8 __attribute__((ext_vector_type(8)));
typedef float f32x4 __attribute__((ext_vector_type(4)));
typedef unsigned short u16x8 __attribute__((ext_vector_type(8)));
typedef unsigned short u16x4 __attribute__((ext_vector_type(4)));
typedef unsigned int   u32x4 __attribute__((ext_vector_type(4)));

__device__ __forceinline__ float sigm(float x){ return 1.f/(1.f+expf(-x)); }
__device__ __forceinline__ float gelu_f(float x){ return 0.5f*x*(1.f+erff(x*0.7071067811865476f)); }
__device__ __forceinline__ unsigned short bfrnd(float f){
  unsigned u = __float_as_uint(f);
  unsigned r = u + 0x7FFFu + ((u>>16)&1u);
  return (unsigned short)(r>>16);
}
__device__ __forceinline__ float bf2f(unsigned short s){
  return __uint_as_float(((unsigned)s)<<16);
}

// ---------------- CA branch ----------------
__global__ void __launch_bounds__(256) k_xstat(const float* __restrict__ x,
                                               float* __restrict__ xh, float* __restrict__ xw){
  int plane = blockIdx.x;
  int tid = threadIdx.x;
  const float* p = x + (size_t)plane*HW_;
  float cs = 0.f;
  for(int h=0;h<256;h++) cs += p[h*256+tid];
  xw[plane*256+tid] = cs*(1.f/256.f);
  float rs = 0.f;
  const f32x4* pr4 = (const f32x4*)(p + (size_t)tid*256);
  #pragma unroll 8
  for(int w=0;w<64;w++){ f32x4 v = pr4[w]; rs += v[0]+v[1]+v[2]+v[3]; }
  xh[plane*256+tid] = rs*(1.f/256.f);
}

__global__ void k_ca_t(const float* __restrict__ xh, const float* __restrict__ xw,
                       const float* __restrict__ w1, const float* __restrict__ b1,
                       const float* __restrict__ bng, const float* __restrict__ bnb,
                       float* __restrict__ t){
  int idx = blockIdx.x*256 + threadIdx.x;
  int p = idx & 511; int m = (idx>>9)&7; int b = idx>>12;
  float acc = b1[m];
  #pragma unroll 8
  for(int c=0;c<C_;c++){
    float yv = (p<256) ? xh[(b*C_+c)*256 + p] : xw[(b*C_+c)*256 + (p-256)];
    acc += w1[m*C_+c]*yv;
  }
  float v = acc*BNINV*bng[m] + bnb[m];
  t[idx] = v * fminf(fmaxf(v+3.f,0.f),6.f)*(1.f/6.f);
}

__global__ void k_ca_a(const float* __restrict__ t,
                       const float* __restrict__ wh, const float* __restrict__ bh,
                       const float* __restrict__ ww, const float* __restrict__ bw,
                       float* __restrict__ ah, float* __restrict__ aw){
  int idx = blockIdx.x*256 + threadIdx.x;
  int p = idx & 511; int co = (idx>>9)&63; int b = idx>>15;
  bool isH = (p<256);
  const float* wm = isH ? wh : ww;
  float acc = isH ? bh[co] : bw[co];
  #pragma unroll
  for(int m=0;m<MIP_;m++) acc += wm[co*MIP_+m]*t[(b*MIP_+m)*512+p];
  float s = sigm(acc);
  if(isH) ah[(b*C_+co)*256+p] = s; else aw[(b*C_+co)*256+(p-256)] = s;
}

// ---------------- weight / input prep (once) ----------------
__global__ void __launch_bounds__(256) k_xprep(const float* __restrict__ x, unsigned short* __restrict__ xb){
  __shared__ float sm[64][65];
  int tid = threadIdx.x;
  int img = blockIdx.x >> 10;
  int p0 = (blockIdx.x & 1023)*64;
  int lane = tid & 63, wq = tid >> 6;
  #pragma unroll
  for(int cc=0; cc<16; ++cc){
    int c = cc*4 + wq;
    sm[c][lane] = x[(size_t)(img*C_+c)*HW_ + p0 + lane];
  }
  __syncthreads();
  int pl = tid >> 2;
  int c0 = (tid & 3) * 16;
  u16x8 lo, hi;
  #pragma unroll
  for(int i=0;i<8;i++)  lo[i] = bfrnd(sm[c0+i][pl]);
  #pragma unroll
  for(int i=0;i<8;i++)  hi[i] = bfrnd(sm[c0+8+i][pl]);
  unsigned short* dst = xb + ((size_t)img*HW_ + p0 + pl)*64 + c0;
  *(u16x8*)(dst)     = lo;
  *(u16x8*)(dst + 8) = hi;
}

__global__ void k_wprep(const float* __restrict__ w, unsigned short* __restrict__ wbt){
  int t = blockIdx.x*256 + threadIdx.x;   // 16384
  const float* src = w + (size_t)t*9;
  int oc = t >> 7, ic = t & 127;
  #pragma unroll
  for(int tap=0; tap<9; ++tap)
    wbt[(size_t)(tap*128+oc)*128 + ic] = bfrnd(src[tap]);
}

__global__ void k_wprep2(const float* __restrict__ pw, const float* __restrict__ w2,
                         const float* __restrict__ hw, unsigned short* __restrict__ pwb,
                         unsigned short* __restrict__ w2b, unsigned short* __restrict__ wb1){
  int t = blockIdx.x*256 + threadIdx.x;   // 24576
  if(t < 8192){ pwb[t] = bfrnd(pw[t]); w2b[t] = bfrnd(w2[t]); }
  wb1[t] = bfrnd(hw[t]);
}

// ---------------- FSAS chain (bf16, pixel-major) ----------------
__global__ void __launch_bounds__(256) k_hid0_mfma(const unsigned short* __restrict__ xb,
                                                   const unsigned short* __restrict__ wb1,
                                                   unsigned short* __restrict__ hid0b){
  int tid = threadIdx.x;
  int lane = tid & 63, wid = tid >> 6;
  int l15 = lane & 15, lk = lane >> 4;
  int p0 = blockIdx.x*128 + wid*32;
  int oc0 = blockIdx.y*96;
  f32x4 acc[6][2];
  #pragma unroll
  for(int m=0;m<6;m++)
    #pragma unroll
    for(int n=0;n<2;n++) acc[m][n] = (f32x4)0.f;
  #pragma unroll
  for(int kk=0; kk<2; ++kk){
    bf16x8 bfr[2];
    #pragma unroll
    for(int n=0;n<2;n++)
      bfr[n] = *(const bf16x8*)(xb + (size_t)(p0 + n*16 + l15)*64 + kk*32 + lk*8);
    #pragma unroll
    for(int m=0;m<6;m++){
      bf16x8 af = *(const bf16x8*)(wb1 + (size_t)(oc0 + m*16 + l15)*64 + kk*32 + lk*8);
      #pragma unroll
      for(int n=0;n<2;n++)
        acc[m][n] = __builtin_amdgcn_mfma_f32_16x16x32_bf16(af, bfr[n], acc[m][n], 0,0,0);
    }
  }
  #pragma unroll
  for(int n=0;n<2;n++){
    int p = p0 + n*16 + l15;
    #pragma unroll
    for(int m=0;m<6;m++){
      u16x4 v;
      #pragma unroll
      for(int r=0;r<4;r++) v[r] = bfrnd(acc[m][n][r]);
      *(u16x4*)(hid0b + (size_t)p*384 + oc0 + m*16 + lk*4) = v;
    }
  }
}

// depthwise 3x3 pad1 on [p][384] bf16.
__global__ void __launch_bounds__(256) k_dw_bf(const unsigned short* __restrict__ hid0b,
                                               const float* __restrict__ wd,
                                               unsigned short* __restrict__ hidb){
  int tid = threadIdx.x;
  int cg = tid & 15;
  int tg = tid >> 4;
  int p0 = blockIdx.x*64;
  int h  = p0 >> 8;
  int w0 = (p0 & 255) + tg*4;
  int chb = blockIdx.y*128 + cg*8;

  float wreg[72];
  {
    const f32x4* wsrc = (const f32x4*)(wd + (size_t)chb*9);
    #pragma unroll
    for(int i=0;i<18;i++){
      f32x4 v = wsrc[i];
      wreg[4*i+0]=v[0]; wreg[4*i+1]=v[1]; wreg[4*i+2]=v[2]; wreg[4*i+3]=v[3];
    }
  }
  float acc[4][8];
  #pragma unroll
  for(int px=0;px<4;px++)
    #pragma unroll
    for(int e=0;e<8;e++) acc[px][e] = 0.f;

  #pragma unroll
  for(int ky=0; ky<3; ++ky){
    int hh = h + ky - 1;
    if((unsigned)hh >= 256u) continue;
    float row[6][8];
    #pragma unroll
    for(int c6=0; c6<6; ++c6){
      int ww = w0 + c6 - 1;
      u16x8 v8 = {0,0,0,0,0,0,0,0};
      if((unsigned)ww < 256u)
        v8 = *(const u16x8*)(hid0b + (size_t)(hh*256+ww)*384 + chb);
      #pragma unroll
      for(int e=0;e<8;e++) row[c6][e] = bf2f(v8[e]);
    }
    #pragma unroll
    for(int kx=0; kx<3; ++kx){
      #pragma unroll
      for(int px=0; px<4; ++px){
        #pragma unroll
        for(int e=0;e<8;e++)
          acc[px][e] += row[px+kx][e] * wreg[e*9 + ky*3 + kx];
      }
    }
  }
  #pragma unroll
  for(int px=0; px<4; ++px){
    u16x8 o8;
    #pragma unroll
    for(int e=0;e<8;e++) o8[e] = bfrnd(acc[px][e]);
    *(u16x8*)(hidb + (size_t)(p0 + tg*4 + px)*384 + chb) = o8;
  }
}

// circular 8x8 conv per patch
__global__ void __launch_bounds__(256) k_circ_bf(const unsigned short* __restrict__ hidb,
                                                 unsigned short* __restrict__ ob){
  __shared__ __align__(16) unsigned short lq[2][64][128];
  __shared__ __align__(16) unsigned short lkk[2][64][128];
  int tid = threadIdx.x;
  #pragma unroll
  for(int it=0; it<8; ++it){
    int s = it*256 + tid;
    int which = s >> 10, rem = s & 1023;
    int pix = rem >> 4, cg = rem & 15;
    int gp = blockIdx.x*2 + which;
    int ph = gp >> 5, pw = gp & 31;
    size_t pg = (size_t)((ph*8 + (pix>>3))*256 + pw*8 + (pix&7));
    *(u16x8*)&lq[which][pix][cg*8]  = *(const u16x8*)(hidb + pg*384 + cg*8);
    *(u16x8*)&lkk[which][pix][cg*8] = *(const u16x8*)(hidb + pg*384 + 128 + cg*8);
  }
  __syncthreads();
  int which = tid >> 7, c = tid & 127;
  float kr[64];
  #pragma unroll
  for(int pix=0;pix<64;pix++) kr[pix] = bf2f(lkk[which][pix][c]);
  float outv[64];
  #pragma unroll
  for(int t2=0;t2<64;t2++) outv[t2] = 0.f;
  #pragma unroll
  for(int u=0;u<8;u++){
    #pragma unroll
    for(int v=0;v<8;v++){
      float qv = bf2f(lq[which][u*8+v][c]);
      #pragma unroll
      for(int i=0;i<8;i++){
        #pragma unroll
        for(int j=0;j<8;j++)
          outv[i*8+j] += qv * kr[((i-u)&7)*8 + ((j-v)&7)];
      }
    }
  }
  __syncthreads();
  #pragma unroll
  for(int t2=0;t2<64;t2++) lq[which][t2][c] = bfrnd(outv[t2]);
  __syncthreads();
  #pragma unroll
  for(int it=0; it<8; ++it){
    int s = it*256 + tid;
    int which2 = s >> 10, rem = s & 1023;
    int pix = rem >> 4, cg = rem & 15;
    int gp = blockIdx.x*2 + which2;
    int ph = gp >> 5, pw = gp & 31;
    size_t pg = (size_t)((ph*8 + (pix>>3))*256 + pw*8 + (pix&7));
    *(u16x8*)(ob + pg*128 + cg*8) = *(u16x8*)&lq[which2][pix][cg*8];
  }
}

// fused LN + (v*on) + proj via MFMA
__global__ void __launch_bounds__(256) k_proj_mfma(const unsigned short* __restrict__ ob,
                      const unsigned short* __restrict__ hidb,
                      const float* __restrict__ lnw, const float* __restrict__ lnb,
                      const unsigned short* __restrict__ pwb, unsigned short* __restrict__ catb){
  __shared__ unsigned int lds32[256*64];
  int tid = threadIdx.x;
  int lane = tid & 63, wid = tid >> 6;
  int p0 = blockIdx.x*256;
  {
    int p = p0 + tid;
    u16x8 o8[16];
    #pragma unroll
    for(int g=0; g<16; ++g) o8[g] = *(const u16x8*)(ob + (size_t)p*128 + g*8);
    float s=0.f, s2=0.f;
    #pragma unroll
    for(int g=0; g<16; ++g)
      #pragma unroll
      for(int e=0; e<8; ++e){ float v = bf2f(o8[g][e]); s += v; s2 += v*v; }
    float m = s*(1.f/C2_);
    float var = s2*(1.f/C2_) - m*m;
    float rs = rsqrtf(var + 1e-5f);
    #pragma unroll
    for(int cg=0; cg<16; ++cg){
      u16x8 v8 = *(const u16x8*)(hidb + (size_t)p*384 + 256 + cg*8);
      unsigned uu[4];
      #pragma unroll
      for(int ee=0; ee<4; ++ee){
        int c = cg*8 + ee*2;
        float on0 = (bf2f(o8[cg][2*ee])   - m)*rs*lnw[c]   + lnb[c];
        float on1 = (bf2f(o8[cg][2*ee+1]) - m)*rs*lnw[c+1] + lnb[c+1];
        float vn0 = bf2f(v8[2*ee])*on0;
        float vn1 = bf2f(v8[2*ee+1])*on1;
        uu[ee] = (unsigned)bfrnd(vn0) | ((unsigned)bfrnd(vn1)<<16);
      }
      int blk = cg ^ (tid & 15);
      u32x4 w4 = {uu[0],uu[1],uu[2],uu[3]};
      *(u32x4*)&lds32[tid*64 + blk*4] = w4;
    }
  }
  __syncthreads();
  int l15 = lane & 15, lk = lane >> 4;
  f32x4 acc[4][4];
  #pragma unroll
  for(int m=0;m<4;m++)
    #pragma unroll
    for(int n=0;n<4;n++) acc[m][n] = (f32x4)0.f;
  int plb = wid*64;
  #pragma unroll
  for(int kk=0; kk<4; ++kk){
    bf16x8 bfr[4];
    #pragma unroll
    for(int n=0;n<4;n++){
      int pl = plb + n*16 + l15;
      int blk = (kk*4 + lk) ^ l15;
      bfr[n] = *(bf16x8*)&lds32[pl*64 + blk*4];
    }
    #pragma unroll
    for(int m=0;m<4;m++){
      bf16x8 af = *(const bf16x8*)(pwb + (size_t)(m*16+l15)*128 + kk*32 + lk*8);
      #pragma unroll
      for(int n=0;n<4;n++)
        acc[m][n] = __builtin_amdgcn_mfma_f32_16x16x32_bf16(af, bfr[n], acc[m][n], 0,0,0);
    }
  }
  #pragma unroll
  for(int n=0;n<4;n++){
    int p = p0 + plb + n*16 + l15;
    #pragma unroll
    for(int m=0;m<4;m++){
      u16x4 v;
      #pragma unroll
      for(int r=0;r<4;r++) v[r] = bfrnd(acc[m][n][r]);
      *(u16x4*)(catb + (size_t)p*128 + 64 + m*16 + lk*4) = v;
    }
  }
}

// ca_out from bf16 xb (pixel-major, no transpose needed)
__global__ void __launch_bounds__(256) k_caout_bf(const unsigned short* __restrict__ xb,
                        const float* __restrict__ ah, const float* __restrict__ aw,
                        unsigned short* __restrict__ catb, int b){
  __shared__ float ah_s[64];
  __shared__ float aw_s[64][65];
  int tid = threadIdx.x;
  int p0 = blockIdx.x*64;
  int h = p0 >> 8;
  int w0 = p0 & 255;
  if(tid < 64) ah_s[tid] = ah[(b*C_+tid)*256 + h];
  {
    int wl = tid & 63, cq = tid >> 6;
    #pragma unroll
    for(int cc=0; cc<16; ++cc){
      int c = cc*4 + cq;
      aw_s[c][wl] = aw[(b*C_+c)*256 + w0 + wl];
    }
  }
  __syncthreads();
  int pl = tid >> 2;
  int c0 = (tid & 3) * 16;
  u16x8 x0 = *(const u16x8*)(xb + (size_t)(p0+pl)*64 + c0);
  u16x8 x1 = *(const u16x8*)(xb + (size_t)(p0+pl)*64 + c0 + 8);
  u16x8 lo, hi;
  #pragma unroll
  for(int e=0;e<8;e++){
    lo[e] = bfrnd(bf2f(x0[e]) * ah_s[c0+e]   * aw_s[c0+e][pl]);
    hi[e] = bfrnd(bf2f(x1[e]) * ah_s[c0+8+e] * aw_s[c0+8+e][pl]);
  }
  unsigned short* dst = catb + (size_t)(p0+pl)*128 + c0;
  *(u16x8*)(dst)     = lo;
  *(u16x8*)(dst + 8) = hi;
}

// 3x3 conv 128->128 pad1 via MFMA, conflict-free LDS layout + T14 stage-ahead.
__global__ void __launch_bounds__(256,3) k_fus1_mfma(const unsigned short* __restrict__ catb,
                                                     const unsigned short* __restrict__ wbt,
                                                     unsigned short* __restrict__ f1b){
  __shared__ __align__(16) unsigned short sA[3][130][32];
  int tid = threadIdx.x;
  int lane = tid & 63, wid = tid >> 6;
  int wm = wid & 1, wn = wid >> 1;
  int bid = blockIdx.x;
  int xcd = bid & 7, idx = bid >> 3;    // 0..127
  int h   = xcd*32 + (idx >> 2);
  int w0  = ((idx >> 1) & 1) * 128;
  int ocb = (idx & 1) * 64 + wn*32;
  int l15 = lane & 15, lk = lane >> 4;

  int srow[7], spxl[7], sicq[7];
  bool sok[7], sld[7];
  #pragma unroll
  for(int it=0; it<7; ++it){
    int s = it*256 + tid;
    sok[it] = (s < 1560);
    int row = s/520;
    int rem = s - row*520;
    int pxl = rem >> 2;
    int icq = rem & 3;
    srow[it]=row; spxl[it]=pxl; sicq[it]=icq;
    int r = h + row - 1;
    int c = w0 + pxl - 1;
    sld[it] = sok[it] && (unsigned)r < 256u && (unsigned)c < 256u;
  }

  u16x8 st[7];
  #pragma unroll
  for(int it=0; it<7; ++it){
    u16x8 v = {0,0,0,0,0,0,0,0};
    if(sld[it]){
      int r = h + srow[it] - 1, c = w0 + spxl[it] - 1;
      v = *(const u16x8*)(catb + (size_t)(r*256 + c)*128 + sicq[it]*8);
    }
    st[it] = v;
  }

  f32x4 acc[4][2];
  #pragma unroll
  for(int i=0;i<4;i++)
    #pragma unroll
    for(int j=0;j<2;j++) acc[i][j] = (f32x4)0.f;

  const unsigned short* wbase = wbt + (size_t)(ocb + l15)*128 + lk*8;

  for(int icc=0; icc<4; ++icc){
    int ic0 = icc*32;
    __syncthreads();
    #pragma unroll
    for(int it=0; it<7; ++it){
      if(sok[it]){
        int blk = sicq[it] ^ ((spxl[it]>>1)&3);
        *(u16x8*)&sA[srow[it]][spxl[it]][blk*8] = st[it];
      }
    }
    __syncthreads();
    if(icc < 3){
      int ic0n = (icc+1)*32;
      #pragma unroll
      for(int it=0; it<7; ++it){
        u16x8 v = {0,0,0,0,0,0,0,0};
        if(sld[it]){
          int r = h + srow[it] - 1, c = w0 + spxl[it] - 1;
          v = *(const u16x8*)(catb + (size_t)(r*256 + c)*128 + ic0n + sicq[it]*8);
        }
        st[it] = v;
      }
    }
    #pragma unroll
    for(int ky=0; ky<3; ++ky){
      bf16x8 wf[3][2];
      #pragma unroll
      for(int kx=0; kx<3; ++kx){
        const unsigned short* wt = wbase + (size_t)(ky*3+kx)*16384 + ic0;
        wf[kx][0] = *(const bf16x8*)(wt);
        wf[kx][1] = *(const bf16x8*)(wt + 2048);
      }
      #pragma unroll
      for(int kx=0; kx<3; ++kx){
        #pragma unroll
        for(int i=0;i<4;++i){
          int rr = wm*64 + i*16 + l15 + kx;
          int blk = lk ^ ((rr>>1)&3);
          bf16x8 a = *(const bf16x8*)&sA[ky][rr][blk*8];
          acc[i][0] = __builtin_amdgcn_mfma_f32_16x16x32_bf16(wf[kx][0], a, acc[i][0], 0,0,0);
          acc[i][1] = __builtin_amdgcn_mfma_f32_16x16x32_bf16(wf[kx][1], a, acc[i][1], 0,0,0);
        }
      }
    }
  }
  #pragma unroll
  for(int i=0;i<4;i++){
    int sp = h*256 + w0 + wm*64 + i*16 + l15;
    #pragma unroll
    for(int j=0;j<2;j++){
      u16x4 v;
      #pragma unroll
      for(int r2=0;r2<4;r2++) v[r2] = bfrnd(acc[i][j][r2]);
      *(u16x4*)(f1b + (size_t)sp*128 + ocb + j*16 + lk*4) = v;
    }
  }
}

// fus2: g = gelu(bn1(f1)); z = x + rs*bn2(conv1x1(g)) -> bf16 z, fused CBAM partials
__global__ void __launch_bounds__(256) k_fus2_mfma(const unsigned short* __restrict__ f1b,
                      const float* __restrict__ x, const unsigned short* __restrict__ w2b,
                      const float* __restrict__ bn1g, const float* __restrict__ bn1b,
                      const float* __restrict__ bn2g, const float* __restrict__ bn2b,
                      const float* __restrict__ rscale, unsigned short* __restrict__ zb,
                      float* __restrict__ psum2, float* __restrict__ pmax2, int b){
  __shared__ unsigned int lds32[128*64];
  __shared__ float smp[4][4][16], smm[4][4][16];
  int tid = threadIdx.x;
  int lane = tid & 63, wid = tid >> 6;
  int p0 = blockIdx.x*128;
  int ic0 = (tid & 15) * 8;
  #pragma unroll
  for(int pass=0; pass<8; ++pass){
    int pl = pass*16 + (tid>>4);
    bf16x8 vv = *(const bf16x8*)(f1b + (size_t)(p0+pl)*128 + ic0);
    unsigned uu[4];
    #pragma unroll
    for(int ee=0; ee<4; ++ee){
      float f0 = bf2f((unsigned short)vv[2*ee])  *BNINV*bn1g[ic0+2*ee]   + bn1b[ic0+2*ee];
      float f1 = bf2f((unsigned short)vv[2*ee+1])*BNINV*bn1g[ic0+2*ee+1] + bn1b[ic0+2*ee+1];
      uu[ee] = (unsigned)bfrnd(gelu_f(f0)) | ((unsigned)bfrnd(gelu_f(f1))<<16);
    }
    int blk = (ic0>>3) ^ (pl&15);
    u32x4 w4 = {uu[0],uu[1],uu[2],uu[3]};
    *(u32x4*)&lds32[pl*64 + blk*4] = w4;
  }
  __syncthreads();
  int l15 = lane & 15, lk = lane >> 4;
  f32x4 acc[4][2];
  #pragma unroll
  for(int m=0;m<4;m++)
    #pragma unroll
    for(int n=0;n<2;n++) acc[m][n] = (f32x4)0.f;
  int pl0 = wid*32 + l15;
  #pragma unroll
  for(int kk=0; kk<4; ++kk){
    bf16x8 bfr[2];
    #pragma unroll
    for(int n=0;n<2;n++){
      int pl = pl0 + n*16;
      int blk = (kk*4 + lk) ^ l15;
      bfr[n] = *(bf16x8*)&lds32[pl*64 + blk*4];
    }
    #pragma unroll
    for(int m=0;m<4;m++){
      bf16x8 af = *(const bf16x8*)(w2b + (size_t)(m*16+l15)*128 + kk*32 + lk*8);
      #pragma unroll
      for(int n=0;n<2;n++)
        acc[m][n] = __builtin_amdgcn_mfma_f32_16x16x32_bf16(af, bfr[n], acc[m][n], 0,0,0);
    }
  }
  float rs = rscale[0];
  float ps[4][4], pm[4][4];
  #pragma unroll
  for(int m=0;m<4;m++)
    #pragma unroll
    for(int r=0;r<4;r++){ ps[m][r]=0.f; pm[m][r]=-INFINITY; }
  #pragma unroll
  for(int n=0;n<2;n++){
    int p = p0 + pl0 + n*16;
    #pragma unroll
    for(int m=0;m<4;m++){
      #pragma unroll
      for(int r=0;r<4;r++){
        int oc = m*16 + lk*4 + r;
        float f = acc[m][n][r]*BNINV*bn2g[oc] + bn2b[oc];
        float zv = x[(size_t)(b*C_+oc)*HW_ + p] + rs*f;
        zb[(size_t)oc*HW_ + p] = bfrnd(zv);
        ps[m][r] += zv; pm[m][r] = fmaxf(pm[m][r], zv);
      }
    }
  }
  #pragma unroll
  for(int off=1; off<16; off<<=1){
    #pragma unroll
    for(int m=0;m<4;m++)
      #pragma unroll
      for(int r=0;r<4;r++){
        ps[m][r] += __shfl_xor(ps[m][r], off, 64);
        pm[m][r] = fmaxf(pm[m][r], __shfl_xor(pm[m][r], off, 64));
      }
  }
  if(l15 == 0){
    #pragma unroll
    for(int m=0;m<4;m++)
      #pragma unroll
      for(int r=0;r<4;r++){
        smp[wid][lk][m*4+r] = ps[m][r];
        smm[wid][lk][m*4+r] = pm[m][r];
      }
  }
  __syncthreads();
  if(tid < 64){
    int m = tid>>4, lkg = (tid>>2)&3, r = tid&3;
    float s = 0.f, mx = -INFINITY;
    #pragma unroll
    for(int w=0;w<4;w++){
      s += smp[w][lkg][m*4+r];
      mx = fmaxf(mx, smm[w][lkg][m*4+r]);
    }
    psum2[blockIdx.x*64 + tid] = s;
    pmax2[blockIdx.x*64 + tid] = mx;
  }
}

// ---------------- CBAM + epilogue (batched over 4 images) ----------------
__global__ void k_cbamred2(const float* __restrict__ psum2, const float* __restrict__ pmax2,
                           float* __restrict__ avgb4, float* __restrict__ maxb4){
  int c = blockIdx.x & 63; int b = blockIdx.x >> 6;
  const float* ps = psum2 + (size_t)b*32768;
  const float* pmx = pmax2 + (size_t)b*32768;
  int tid = threadIdx.x;  // 256
  float s = ps[(size_t)tid*64 + c] + ps[(size_t)(tid+256)*64 + c];
  float m = fmaxf(pmx[(size_t)tid*64 + c], pmx[(size_t)(tid+256)*64 + c]);
  __shared__ float ss[256], sm[256];
  ss[tid]=s; sm[tid]=m; __syncthreads();
  for(int off=128; off>0; off>>=1){
    if(tid<off){ ss[tid]+=ss[tid+off]; sm[tid]=fmaxf(sm[tid],sm[tid+off]); }
    __syncthreads();
  }
  if(tid==0){ avgb4[b*64+c]=ss[0]*(1.f/HW_); maxb4[b*64+c]=sm[0]; }
}

__global__ void k_cbammlp(const float* __restrict__ avgb4, const float* __restrict__ maxb4,
                          const float* __restrict__ w1, const float* __restrict__ w2,
                          float* __restrict__ catt4){
  __shared__ float h1s[4][8];
  int tid = threadIdx.x;   // 256 = 4 batches x 64 ch
  int b = tid >> 6, cl = tid & 63;
  if(cl < 8){
    const float* src = (cl<4)? avgb4 + b*64 : maxb4 + b*64;
    int r = cl & 3;
    float s = 0.f;
    for(int c=0;c<C_;c++) s += w1[r*C_+c]*src[c];
    h1s[b][cl] = fmaxf(s,0.f);
  }
  __syncthreads();
  float a = 0.f;
  #pragma unroll
  for(int r=0;r<4;r++) a += w2[cl*4+r]*(h1s[b][r]+h1s[b][r+4]);
  catt4[b*64+cl] = sigm(a);
}

__global__ void k_chatt(const unsigned short* __restrict__ z4, const float* __restrict__ catt4,
                        float* __restrict__ samean4, float* __restrict__ samax4){
  int gp = blockIdx.x*256 + threadIdx.x;   // 0..262143
  int b = gp >> 16; int p = gp & 65535;
  const unsigned short* zb = z4 + (size_t)b*C_*HW_;
  const float* ct = catt4 + b*64;
  float s = 0.f, m = -INFINITY;
  #pragma unroll 8
  for(int c=0;c<C_;c++){
    float v = bf2f(zb[(size_t)c*HW_+p])*ct[c];
    s += v; m = fmaxf(m,v);
  }
  samean4[gp] = s*(1.f/C_);
  samax4[gp] = m;
}

__global__ void k_saconv(const float* __restrict__ samean4, const float* __restrict__ samax4,
                         const float* __restrict__ saw, float* __restrict__ att4){
  int gp = blockIdx.x*256 + threadIdx.x;
  int b = gp >> 16; int p = gp & 65535;
  int base = b << 16;
  int h = p>>8, w = p&255;
  float acc = 0.f;
  #pragma unroll
  for(int ky=0;ky<7;ky++){
    int hh = h+ky-3; if((unsigned)hh>=256u) continue;
    #pragma unroll
    for(int kx=0;kx<7;kx++){
      int ww2 = w+kx-3; if((unsigned)ww2>=256u) continue;
      int q = base + hh*256+ww2;
      acc += samean4[q]*saw[ky*7+kx] + samax4[q]*saw[49+ky*7+kx];
    }
  }
  att4[gp] = sigm(acc);
}

__global__ void k_final(const unsigned short* __restrict__ z4, const float* __restrict__ catt4,
                        const float* __restrict__ att4, float* __restrict__ out){
  int gp = blockIdx.x*256 + threadIdx.x;   // (b,p)
  int b = gp >> 16; int p = gp & 65535;
  int c = blockIdx.y;
  float v = bf2f(z4[((size_t)(b*C_+c))*HW_ + p]) * catt4[b*64+c] * att4[gp];
  out[((size_t)(b*C_+c))*HW_ + p] = gelu_f(v);
}

extern "C" void kernel_launch(void* const* d_in, const int* in_sizes, int n_in,
                              void* d_out, int out_size, void* d_ws, size_t ws_size,
                              hipStream_t stream){
  const float* x            = (const float*)d_in[0];
  const float* ca_conv1_w   = (const float*)d_in[1];
  const float* ca_conv1_b   = (const float*)d_in[2];
  const float* ca_bn_g      = (const float*)d_in[3];
  const float* ca_bn_b      = (const float*)d_in[4];
  const float* ca_convh_w   = (const float*)d_in[5];
  const float* ca_convh_b   = (const float*)d_in[6];
  const float* ca_convw_w   = (const float*)d_in[7];
  const float* ca_convw_b   = (const float*)d_in[8];
  const float* fsas_hidden_w= (const float*)d_in[9];
  const float* fsas_dw_w    = (const float*)d_in[10];
  const float* fsas_proj_w  = (const float*)d_in[11];
  const float* ln_w         = (const float*)d_in[12];
  const float* ln_b         = (const float*)d_in[13];
  const float* fus_conv1_w  = (const float*)d_in[14];
  const float* fus_bn1_g    = (const float*)d_in[15];
  const float* fus_bn1_b    = (const float*)d_in[16];
  const float* fus_conv2_w  = (const float*)d_in[17];
  const float* fus_bn2_g    = (const float*)d_in[18];
  const float* fus_bn2_b    = (const float*)d_in[19];
  const float* cbam_mlp1_w  = (const float*)d_in[20];
  const float* cbam_mlp2_w  = (const float*)d_in[21];
  const float* cbam_sa_w    = (const float*)d_in[22];
  const float* rscale       = (const float*)d_in[23];
  float* out = (float*)d_out;
  float* ws  = (float*)d_ws;

  float* xh      = ws + 0;        // 65536
  float* xw      = ws + 65536;    // 65536
  float* t       = ws + 131072;   // 16384
  float* ah      = ws + 147456;   // 65536
  float* aw      = ws + 212992;   // 65536
  float* catt4   = ws + 278528;   // 256
  float* avgb4   = ws + 278784;   // 256
  float* maxb4   = ws + 279040;   // 256
  float* psum2   = ws + 279296;   // 4*32768
  float* pmax2   = ws + 410368;   // 4*32768
  float* samean4 = ws + 541440;   // 262144
  float* samax4  = ws + 803584;   // 262144
  float* att4    = ws + 1065728;  // 262144
  float* big     = ws + 1327872;
  unsigned short* catb  = (unsigned short*)(big);             // [HW][128] u16
  unsigned short* f1b   = (unsigned short*)(big + 4194304);   // [HW][128] u16
  unsigned short* z4    = (unsigned short*)(big + 8388608);   // [4][64][HW] u16
  unsigned short* xb    = (unsigned short*)(big + 16777216);  // [4*HW][64] u16
  unsigned short* hid0b = (unsigned short*)(big + 25165824);  // [HW][384] u16
  unsigned short* hidb  = (unsigned short*)(big + 37748736);  // [HW][384] u16
  unsigned short* obuf  = (unsigned short*)(big + 50331648);  // [HW][128] u16
  unsigned short* wbt   = (unsigned short*)(big + 54525952);  // 147456 u16
  unsigned short* wb1   = (unsigned short*)(big + 54599680);  // 24576 u16
  unsigned short* pwb   = (unsigned short*)(big + 54611968);  // 8192 u16
  unsigned short* w2b   = (unsigned short*)(big + 54616064);  // 8192 u16

  k_xstat<<<256,256,0,stream>>>(x, xh, xw);
  k_ca_t<<<64,256,0,stream>>>(xh, xw, ca_conv1_w, ca_conv1_b, ca_bn_g, ca_bn_b, t);
  k_ca_a<<<512,256,0,stream>>>(t, ca_convh_w, ca_convh_b, ca_convw_w, ca_convw_b, ah, aw);
  k_xprep<<<4096,256,0,stream>>>(x, xb);
  k_wprep<<<64,256,0,stream>>>(fus_conv1_w, wbt);
  k_wprep2<<<96,256,0,stream>>>(fsas_proj_w, fus_conv2_w, fsas_hidden_w, pwb, w2b, wb1);

  for(int b=0;b<4;b++){
    k_hid0_mfma<<<dim3(512,4),256,0,stream>>>(xb + (size_t)b*HW_*64, wb1, hid0b);
    k_dw_bf<<<dim3(1024,3),256,0,stream>>>(hid0b, fsas_dw_w, hidb);
    k_circ_bf<<<512,256,0,stream>>>(hidb, obuf);
    k_proj_mfma<<<256,256,0,stream>>>(obuf, hidb, ln_w, ln_b, pwb, catb);
    k_caout_bf<<<1024,256,0,stream>>>(xb + (size_t)b*HW_*64, ah, aw, catb, b);
    k_fus1_mfma<<<1024,256,0,stream>>>(catb, wbt, f1b);
    k_fus2_mfma<<<512,256,0,stream>>>(f1b, x, w2b, fus_bn1_g, fus_bn1_b, fus_bn2_g, fus_bn2_b,
                                      rscale, z4 + (size_t)b*C_*HW_,
                                      psum2 + (size_t)b*32768, pmax2 + (size_t)b*32768, b);
  }

  k_cbamred2<<<256,256,0,stream>>>(psum2, pmax2, avgb4, maxb4);
  k_cbammlp<<<1,256,0,stream>>>(avgb4, maxb4, cbam_mlp1_w, cbam_mlp2_w, catt4);
  k_chatt<<<1024,256,0,stream>>>(z4, catt4, samean4, samax4);
  k_saconv<<<1024,256,0,stream>>>(samean4, samax4, cbam_sa_w, att4);
  k_final<<<dim3(1024,64),256,0,stream>>>(z4, catt4, att4, out);
}